// Round 9
// baseline (175.273 us; speedup 1.0000x reference)
//
#include <hip/hip_runtime.h>
#include <cstdint>
#include <cstddef>

typedef float f32x4 __attribute__((ext_vector_type(4)));

constexpr int BB = 16, CC = 3, HH = 512, WW = 512;
constexpr int HW = HH * WW;
constexpr float RATIO = 0.12f;
constexpr int TR = 16;               // rows per tile
constexpr int NBLK = 1024;           // 2 half-blocks x 512 (image,tile) groups

// ws: mmc[48] uints: [0..16) per-image min bits, [16..32) max bits,
// [32..48) arrival counters.  Values >= 0 -> uint order == float order.

__global__ void initc(unsigned int* mmc) {
    int i = threadIdx.x;
    if (i < 16)      mmc[i] = 0x7F800000u;   // +inf
    else if (i < 48) mmc[i] = 0u;            // max identity + counters
}

// One block = (image b, 16-row tile, filter-half h).  Phase A: stage tile+halo
// channel-max into LDS (img read ONCE from HBM), per-image min/max atomics,
// release arrival.  Per-image 64-way barrier (thread 0 spins).  Phase B: pure
// LDS->stores, plane-pair-sequential (2 active streams/block, round-6 pattern).
// All 1024 blocks co-resident: 256 thr, LDS 37KB, launch_bounds(256,4).
__global__ __launch_bounds__(256, 4) void fused(
        const float* __restrict__ img, float* __restrict__ out,
        unsigned int* __restrict__ mmc) {
    int bid  = blockIdx.x;
    int h    = bid & 1;                 // filter half: filters 4h..4h+3
    int g    = bid >> 1;                // 0..511 = (image,tile)
    int b    = g >> 5;
    int tile = g & 31;
    int t    = threadIdx.x;
    int tile0 = tile * TR;

    __shared__ float ld[(TR + 2) * WW];   // 36864 B
    __shared__ float sred[8];
    __shared__ float sthr;

    // ---- phase A: stage 18 channel-max rows + block min/max ----
    const float* ib = img + (size_t)b * CC * HW;
    float mn = 3.4e38f, mx = 0.0f;
    #pragma unroll
    for (int s = 0; s < 9; ++s) {
        int v  = t + (s << 8);          // vec4 index 0..2303
        int vr = v >> 7;                // lds row 0..17
        int vc = (v & 127) << 2;        // col 0..508
        int g2 = min(max(tile0 - 1 + vr, 0), HH - 1);
        const float* rb = ib + (size_t)g2 * WW + vc;
        f32x4 a0 = *(const f32x4*)(rb);
        f32x4 a1 = *(const f32x4*)(rb + HW);
        f32x4 a2 = *(const f32x4*)(rb + 2 * HW);
        f32x4 q;
        q.x = fmaxf(fmaxf(a0.x, a1.x), a2.x);
        q.y = fmaxf(fmaxf(a0.y, a1.y), a2.y);
        q.z = fmaxf(fmaxf(a0.z, a1.z), a2.z);
        q.w = fmaxf(fmaxf(a0.w, a1.w), a2.w);
        *(f32x4*)&ld[vr * WW + vc] = q;
        mn = fminf(mn, fminf(fminf(q.x, q.y), fminf(q.z, q.w)));
        mx = fmaxf(mx, fmaxf(fmaxf(q.x, q.y), fmaxf(q.z, q.w)));
    }
    #pragma unroll
    for (int s = 32; s > 0; s >>= 1) {
        mn = fminf(mn, __shfl_xor(mn, s, 64));
        mx = fmaxf(mx, __shfl_xor(mx, s, 64));
    }
    int wave = t >> 6;
    if ((t & 63) == 0) { sred[wave] = mn; sred[4 + wave] = mx; }
    __syncthreads();

    // ---- per-image barrier: atomics + release arrival; t0 spins ----
    if (t == 0) {
        float m0 = fminf(fminf(sred[0], sred[1]), fminf(sred[2], sred[3]));
        float m1 = fmaxf(fmaxf(sred[4], sred[5]), fmaxf(sred[6], sred[7]));
        atomicMin(&mmc[b],      __float_as_uint(m0));
        atomicMax(&mmc[16 + b], __float_as_uint(m1));
        __hip_atomic_fetch_add(&mmc[32 + b], 1u, __ATOMIC_ACQ_REL,
                               __HIP_MEMORY_SCOPE_AGENT);
        while (__hip_atomic_load(&mmc[32 + b], __ATOMIC_ACQUIRE,
                                 __HIP_MEMORY_SCOPE_AGENT) < 64u)
            __builtin_amdgcn_s_sleep(2);
        unsigned lo = __hip_atomic_load(&mmc[b], __ATOMIC_ACQUIRE,
                                        __HIP_MEMORY_SCOPE_AGENT);
        unsigned hi = __hip_atomic_load(&mmc[16 + b], __ATOMIC_ACQUIRE,
                                        __HIP_MEMORY_SCOPE_AGENT);
        sthr = (__uint_as_float(hi) - __uint_as_float(lo)) * RATIO;
    }
    __syncthreads();
    float thr = sthr;

    // ---- phase B: 4 filters, plane-pair sequential ----
    int c  = (t & 127) << 2;
    int cl = max(c - 1, 0), cr = min(c + 4, WW - 1);
    int rb2 = t >> 7;                   // 0 or 1

    #pragma unroll
    for (int fi = 0; fi < 4; ++fi) {
        int f = (h << 2) + fi;
        size_t planep = (size_t)((f * BB + b) * 2) * HW;
        float* outp = out + planep;
        float* outn = outp + HW;
        #pragma unroll
        for (int j = 0; j < 8; ++j) {
            int orow = (j << 1) + rb2;  // 0..15 within tile
            const float* T = &ld[orow * WW];
            const float* M = &ld[(orow + 1) * WW];
            const float* P = &ld[(orow + 2) * WW];
            float vt[6], vm[6], vp[6];
            { f32x4 q = *(const f32x4*)(T + c);
              vt[0] = T[cl]; vt[1] = q.x; vt[2] = q.y; vt[3] = q.z; vt[4] = q.w; vt[5] = T[cr]; }
            { f32x4 q = *(const f32x4*)(M + c);
              vm[0] = M[cl]; vm[1] = q.x; vm[2] = q.y; vm[3] = q.z; vm[4] = q.w; vm[5] = M[cr]; }
            { f32x4 q = *(const f32x4*)(P + c);
              vp[0] = P[cl]; vp[1] = q.x; vp[2] = q.y; vp[3] = q.z; vp[4] = q.w; vp[5] = P[cr]; }

            float d0, d1, d2, d3;
            switch (f) {   // formulas verified absmax==0.0 in rounds 1-8
                case 0: d0 = vm[0]-vp[2]; d1 = vm[1]-vp[3]; d2 = vm[2]-vp[4]; d3 = vm[3]-vp[5]; break;
                case 1: d0 = vt[2]-vm[0]; d1 = vt[3]-vm[1]; d2 = vt[4]-vm[2]; d3 = vt[5]-vm[3]; break;
                case 2: d0 = vp[1]-vt[2]; d1 = vp[2]-vt[3]; d2 = vp[3]-vt[4]; d3 = vp[4]-vt[5]; break;
                case 3: d0 = vt[0]-vp[1]; d1 = vt[1]-vp[2]; d2 = vt[2]-vp[3]; d3 = vt[3]-vp[4]; break;
                case 4: d0 = vm[2]-vm[1]; d1 = vm[3]-vm[2]; d2 = vm[4]-vm[3]; d3 = vm[5]-vm[4]; break;
                case 5: d0 = vt[1]-vm[1]; d1 = vt[2]-vm[2]; d2 = vt[3]-vm[3]; d3 = vt[4]-vm[4]; break;
                case 6: d0 = vt[2]-vm[1]; d1 = vt[3]-vm[2]; d2 = vt[4]-vm[3]; d3 = vt[5]-vm[4]; break;
                default:d0 = vt[0]-vm[1]; d1 = vt[1]-vm[2]; d2 = vt[2]-vm[3]; d3 = vt[3]-vm[4]; break;
            }
            f32x4 qp, qn;
            qp.x = (fmaxf(d0, 0.f) >= thr) ? 1.f : 0.f;
            qp.y = (fmaxf(d1, 0.f) >= thr) ? 1.f : 0.f;
            qp.z = (fmaxf(d2, 0.f) >= thr) ? 1.f : 0.f;
            qp.w = (fmaxf(d3, 0.f) >= thr) ? 1.f : 0.f;
            qn.x = (fmaxf(-d0, 0.f) >= thr) ? 1.f : 0.f;
            qn.y = (fmaxf(-d1, 0.f) >= thr) ? 1.f : 0.f;
            qn.z = (fmaxf(-d2, 0.f) >= thr) ? 1.f : 0.f;
            qn.w = (fmaxf(-d3, 0.f) >= thr) ? 1.f : 0.f;

            size_t po = (size_t)(tile0 + orow) * WW + c;
            *(f32x4*)(outp + po) = qp;
            *(f32x4*)(outn + po) = qn;
        }
    }
}

extern "C" void kernel_launch(void* const* d_in, const int* in_sizes, int n_in,
                              void* d_out, int out_size, void* d_ws, size_t ws_size,
                              hipStream_t stream) {
    const float* img = (const float*)d_in[0];
    float* out = (float*)d_out;
    unsigned int* mmc = (unsigned int*)d_ws;

    initc<<<1, 64, 0, stream>>>(mmc);
    fused<<<NBLK, 256, 0, stream>>>(img, out, mmc);
}

// Round 10
// 74.504 us; speedup vs baseline: 2.3525x; 2.3525x over previous
//
#include <hip/hip_runtime.h>
#include <cstdint>
#include <cstddef>

typedef float f32x4 __attribute__((ext_vector_type(4)));

constexpr int BB = 16, CC = 3, HH = 512, WW = 512;
constexpr int HW = HH * WW;
constexpr float RATIO = 0.12f;
constexpr int TR = 16;               // rows per k2 tile
constexpr int TILES = HH / TR;       // 32 tiles per image

// ws layout: pmin[4096] @0, pmax[4096] @16384.  No imgv: k2 recomputes
// channel-max from img (L3-resident after k1) during LDS staging.

__global__ __launch_bounds__(256) void k1_minmax(
        const float* __restrict__ img, float* __restrict__ pmin,
        float* __restrict__ pmax) {
    int t    = blockIdx.x * 256 + threadIdx.x;
    int off4 = t << 2;                 // 4 pixels per thread
    int b    = off4 / HW;              // uniform per block (256 blocks/image)
    int off  = off4 - b * HW;
    const float* base = img + (size_t)b * CC * HW + off;
    f32x4 c0 = *(const f32x4*)(base);
    f32x4 c1 = *(const f32x4*)(base + HW);
    f32x4 c2 = *(const f32x4*)(base + 2 * HW);
    f32x4 v;
    v.x = fmaxf(fmaxf(c0.x, c1.x), c2.x);
    v.y = fmaxf(fmaxf(c0.y, c1.y), c2.y);
    v.z = fmaxf(fmaxf(c0.z, c1.z), c2.z);
    v.w = fmaxf(fmaxf(c0.w, c1.w), c2.w);

    float mn = fminf(fminf(v.x, v.y), fminf(v.z, v.w));
    float mx = fmaxf(fmaxf(v.x, v.y), fmaxf(v.z, v.w));
    #pragma unroll
    for (int s = 32; s > 0; s >>= 1) {
        mn = fminf(mn, __shfl_xor(mn, s, 64));
        mx = fmaxf(mx, __shfl_xor(mx, s, 64));
    }
    __shared__ float smn[4], smx[4];
    int wave = threadIdx.x >> 6;
    if ((threadIdx.x & 63) == 0) { smn[wave] = mn; smx[wave] = mx; }
    __syncthreads();
    if (threadIdx.x == 0) {
        pmin[blockIdx.x] = fminf(fminf(smn[0], smn[1]), fminf(smn[2], smn[3]));
        pmax[blockIdx.x] = fmaxf(fmaxf(smx[0], smx[1]), fmaxf(smx[2], smx[3]));
    }
}

// One block = one (filter-PAIR, image, 16-row tile); stages the tile once and
// writes TWO filters' pos/neg plane pairs sequentially (always 2 active
// contiguous 32KB streams -> round-6 write pattern, half the stage traffic).
// The 4 sibling blocks of one (image,tile) land on the SAME XCD (bid mod 8):
// first pulls the img tile from clean L3, others hit that XCD's L2.
__global__ __launch_bounds__(256, 4) void k2_edges(
        const float* __restrict__ img, const float* __restrict__ pmin,
        const float* __restrict__ pmax, float* __restrict__ out) {
    int bid = blockIdx.x;
    int x   = bid & 7;                  // XCD slot
    int m   = bid >> 3;
    int fp  = m & 3;                    // filter pair: filters 2fp, 2fp+1
    int g   = ((m >> 2) << 3) + x;      // group 0..511 = (image,tile)
    int b    = g >> 5;
    int tile = g & 31;
    int t    = threadIdx.x;

    // ---- per-image threshold from k1's 256 partials ----
    __shared__ float sred[8];
    {
        float mlo = pmin[(b << 8) + t];
        float mhi = pmax[(b << 8) + t];
        #pragma unroll
        for (int s = 32; s > 0; s >>= 1) {
            mlo = fminf(mlo, __shfl_xor(mlo, s, 64));
            mhi = fmaxf(mhi, __shfl_xor(mhi, s, 64));
        }
        if ((t & 63) == 0) { sred[t >> 6] = mlo; sred[4 + (t >> 6)] = mhi; }
    }

    // ---- stage 18 channel-max rows (tile + halo, row-clamped) into LDS ----
    __shared__ float ld[(TR + 2) * WW];   // 36864 B
    int tile0 = tile * TR;
    const float* ib = img + (size_t)b * CC * HW;
    #pragma unroll
    for (int s = 0; s < 9; ++s) {
        int v  = t + (s << 8);          // vec4 index 0..2303
        int vr = v >> 7;                // lds row 0..17
        int vc = (v & 127) << 2;        // col 0..508
        int g2 = min(max(tile0 - 1 + vr, 0), HH - 1);
        const float* rb = ib + (size_t)g2 * WW + vc;
        f32x4 a0 = *(const f32x4*)(rb);
        f32x4 a1 = *(const f32x4*)(rb + HW);
        f32x4 a2 = *(const f32x4*)(rb + 2 * HW);
        f32x4 q;
        q.x = fmaxf(fmaxf(a0.x, a1.x), a2.x);
        q.y = fmaxf(fmaxf(a0.y, a1.y), a2.y);
        q.z = fmaxf(fmaxf(a0.z, a1.z), a2.z);
        q.w = fmaxf(fmaxf(a0.w, a1.w), a2.w);
        *(f32x4*)&ld[vr * WW + vc] = q;
    }
    __syncthreads();
    float thr = (fmaxf(fmaxf(sred[4], sred[5]), fmaxf(sred[6], sred[7]))
               - fminf(fminf(sred[0], sred[1]), fminf(sred[2], sred[3]))) * RATIO;

    // ---- compute + store: 2 filters x 8 iterations of (2 rows x 512 cols) ----
    int c  = (t & 127) << 2;
    int cl = max(c - 1, 0), cr = min(c + 4, WW - 1);
    int rb2 = t >> 7;                   // 0 or 1

    #pragma unroll
    for (int fi = 0; fi < 2; ++fi) {
        int f = (fp << 1) | fi;
        size_t planep = (size_t)((f * BB + b) * 2) * HW;
        float* outp = out + planep;
        float* outn = outp + HW;
        #pragma unroll
        for (int j = 0; j < 8; ++j) {
            int orow = (j << 1) + rb2;  // 0..15 within tile
            const float* T = &ld[orow * WW];        // global row rr-1 (clamped)
            const float* M = &ld[(orow + 1) * WW];  // global row rr
            const float* P = &ld[(orow + 2) * WW];  // global row rr+1 (clamped)
            float vt[6], vm[6], vp[6];
            { f32x4 q = *(const f32x4*)(T + c);
              vt[0] = T[cl]; vt[1] = q.x; vt[2] = q.y; vt[3] = q.z; vt[4] = q.w; vt[5] = T[cr]; }
            { f32x4 q = *(const f32x4*)(M + c);
              vm[0] = M[cl]; vm[1] = q.x; vm[2] = q.y; vm[3] = q.z; vm[4] = q.w; vm[5] = M[cr]; }
            { f32x4 q = *(const f32x4*)(P + c);
              vp[0] = P[cl]; vp[1] = q.x; vp[2] = q.y; vp[3] = q.z; vp[4] = q.w; vp[5] = P[cr]; }

            float d0, d1, d2, d3;
            switch (f) {   // formulas verified absmax==0.0 in rounds 1-9
                case 0: d0 = vm[0]-vp[2]; d1 = vm[1]-vp[3]; d2 = vm[2]-vp[4]; d3 = vm[3]-vp[5]; break;
                case 1: d0 = vt[2]-vm[0]; d1 = vt[3]-vm[1]; d2 = vt[4]-vm[2]; d3 = vt[5]-vm[3]; break;
                case 2: d0 = vp[1]-vt[2]; d1 = vp[2]-vt[3]; d2 = vp[3]-vt[4]; d3 = vp[4]-vt[5]; break;
                case 3: d0 = vt[0]-vp[1]; d1 = vt[1]-vp[2]; d2 = vt[2]-vp[3]; d3 = vt[3]-vp[4]; break;
                case 4: d0 = vm[2]-vm[1]; d1 = vm[3]-vm[2]; d2 = vm[4]-vm[3]; d3 = vm[5]-vm[4]; break;
                case 5: d0 = vt[1]-vm[1]; d1 = vt[2]-vm[2]; d2 = vt[3]-vm[3]; d3 = vt[4]-vm[4]; break;
                case 6: d0 = vt[2]-vm[1]; d1 = vt[3]-vm[2]; d2 = vt[4]-vm[3]; d3 = vt[5]-vm[4]; break;
                default:d0 = vt[0]-vm[1]; d1 = vt[1]-vm[2]; d2 = vt[2]-vm[3]; d3 = vt[3]-vm[4]; break;
            }
            f32x4 qp, qn;
            qp.x = (fmaxf(d0, 0.f) >= thr) ? 1.f : 0.f;
            qp.y = (fmaxf(d1, 0.f) >= thr) ? 1.f : 0.f;
            qp.z = (fmaxf(d2, 0.f) >= thr) ? 1.f : 0.f;
            qp.w = (fmaxf(d3, 0.f) >= thr) ? 1.f : 0.f;
            qn.x = (fmaxf(-d0, 0.f) >= thr) ? 1.f : 0.f;
            qn.y = (fmaxf(-d1, 0.f) >= thr) ? 1.f : 0.f;
            qn.z = (fmaxf(-d2, 0.f) >= thr) ? 1.f : 0.f;
            qn.w = (fmaxf(-d3, 0.f) >= thr) ? 1.f : 0.f;

            size_t po = (size_t)(tile0 + orow) * WW + c;
            *(f32x4*)(outp + po) = qp;
            *(f32x4*)(outn + po) = qn;
        }
    }
}

extern "C" void kernel_launch(void* const* d_in, const int* in_sizes, int n_in,
                              void* d_out, int out_size, void* d_ws, size_t ws_size,
                              hipStream_t stream) {
    const float* img = (const float*)d_in[0];
    float* out  = (float*)d_out;
    float* pmin = (float*)d_ws;
    float* pmax = (float*)((char*)d_ws + 16384);

    k1_minmax<<<4096, 256, 0, stream>>>(img, pmin, pmax);
    k2_edges<<<4 * BB * TILES, 256, 0, stream>>>(img, pmin, pmax, out);
}

// Round 11
// 66.752 us; speedup vs baseline: 2.6257x; 1.1161x over previous
//
#include <hip/hip_runtime.h>
#include <cstdint>
#include <cstddef>

typedef float f32x4 __attribute__((ext_vector_type(4)));

constexpr int BB = 16, CC = 3, HH = 512, WW = 512;
constexpr int HW = HH * WW;
constexpr float RATIO = 0.12f;
constexpr int TR = 16;               // rows per k2 tile
constexpr int TILES = HH / TR;       // 32 tiles per image

// ws layout: pmin[4096] @0, pmax[4096] @16384.

__global__ __launch_bounds__(256) void k1_minmax(
        const float* __restrict__ img, float* __restrict__ pmin,
        float* __restrict__ pmax) {
    int t    = blockIdx.x * 256 + threadIdx.x;
    int off4 = t << 2;                 // 4 pixels per thread
    int b    = off4 / HW;              // uniform per block (256 blocks/image)
    int off  = off4 - b * HW;
    const float* base = img + (size_t)b * CC * HW + off;
    f32x4 c0 = *(const f32x4*)(base);
    f32x4 c1 = *(const f32x4*)(base + HW);
    f32x4 c2 = *(const f32x4*)(base + 2 * HW);
    f32x4 v;
    v.x = fmaxf(fmaxf(c0.x, c1.x), c2.x);
    v.y = fmaxf(fmaxf(c0.y, c1.y), c2.y);
    v.z = fmaxf(fmaxf(c0.z, c1.z), c2.z);
    v.w = fmaxf(fmaxf(c0.w, c1.w), c2.w);

    float mn = fminf(fminf(v.x, v.y), fminf(v.z, v.w));
    float mx = fmaxf(fmaxf(v.x, v.y), fmaxf(v.z, v.w));
    #pragma unroll
    for (int s = 32; s > 0; s >>= 1) {
        mn = fminf(mn, __shfl_xor(mn, s, 64));
        mx = fmaxf(mx, __shfl_xor(mx, s, 64));
    }
    __shared__ float smn[4], smx[4];
    int wave = threadIdx.x >> 6;
    if ((threadIdx.x & 63) == 0) { smn[wave] = mn; smx[wave] = mx; }
    __syncthreads();
    if (threadIdx.x == 0) {
        pmin[blockIdx.x] = fminf(fminf(smn[0], smn[1]), fminf(smn[2], smn[3]));
        pmax[blockIdx.x] = fmaxf(fmaxf(smx[0], smx[1]), fmaxf(smx[2], smx[3]));
    }
}

// Round-6 structure (champion, 65.6us) with ONE change: LDS tile = exactly
// 16 rows = 32768B -> 5 blocks/CU (was 18 rows/36.9KB -> 4).  Halo rows live
// in 6 registers per thread (waves 0-1: top halo for j=0; waves 2-3: bottom
// halo for j=7 -- wave-uniform), prefetched at block start so latency hides
// under the stage loop.  launch_bounds(256,8) caps VGPR<=64 so occupancy is
// LDS-bound at 5.  Grid/swizzle/write pattern/math identical to round 6.
__global__ __launch_bounds__(256, 8) void k2_edges(
        const float* __restrict__ img, const float* __restrict__ pmin,
        const float* __restrict__ pmax, float* __restrict__ out) {
    int bid = blockIdx.x;
    int x   = bid & 7;                  // XCD slot
    int m   = bid >> 3;
    int f   = m & 7;                    // filter
    int g   = ((m >> 3) << 3) + x;      // group 0..511 = (image,tile)
    int b    = g >> 5;
    int tile = g & 31;
    int t    = threadIdx.x;
    int tile0 = tile * TR;

    __shared__ float ld[TR * WW];       // 32768 B exactly (also thr scratch)

    const float* ib = img + (size_t)b * CC * HW;

    // ---- halo prefetch into registers (one clamped row per thread-half) ----
    int hc  = (t & 127) << 2;
    int hcl = max(hc - 1, 0), hcr = min(hc + 4, WW - 1);
    int hrow = (t < 128) ? max(tile0 - 1, 0) : min(tile0 + TR, HH - 1);
    const float* hb = ib + (size_t)hrow * WW;
    float hal[6];
    {
        f32x4 a0 = *(const f32x4*)(hb + hc);
        f32x4 a1 = *(const f32x4*)(hb + HW + hc);
        f32x4 a2 = *(const f32x4*)(hb + 2 * HW + hc);
        hal[1] = fmaxf(fmaxf(a0.x, a1.x), a2.x);
        hal[2] = fmaxf(fmaxf(a0.y, a1.y), a2.y);
        hal[3] = fmaxf(fmaxf(a0.z, a1.z), a2.z);
        hal[4] = fmaxf(fmaxf(a0.w, a1.w), a2.w);
        hal[0] = fmaxf(fmaxf(hb[hcl], hb[HW + hcl]), hb[2 * HW + hcl]);
        hal[5] = fmaxf(fmaxf(hb[hcr], hb[HW + hcr]), hb[2 * HW + hcr]);
    }

    // ---- per-image threshold from k1's 256 partials (ld[0..7] scratch) ----
    {
        float mlo = pmin[(b << 8) + t];
        float mhi = pmax[(b << 8) + t];
        #pragma unroll
        for (int s = 32; s > 0; s >>= 1) {
            mlo = fminf(mlo, __shfl_xor(mlo, s, 64));
            mhi = fmaxf(mhi, __shfl_xor(mhi, s, 64));
        }
        if ((t & 63) == 0) { ld[t >> 6] = mlo; ld[4 + (t >> 6)] = mhi; }
    }
    __syncthreads();
    float thr = (fmaxf(fmaxf(ld[4], ld[5]), fmaxf(ld[6], ld[7]))
               - fminf(fminf(ld[0], ld[1]), fminf(ld[2], ld[3]))) * RATIO;
    __syncthreads();                    // thr in regs; ld free for staging

    // ---- stage 16 channel-max rows (no halo) into LDS ----
    #pragma unroll
    for (int s = 0; s < 8; ++s) {
        int v  = t + (s << 8);          // vec4 index 0..2047
        int vr = v >> 7;                // lds row 0..15
        int vc = (v & 127) << 2;        // col 0..508
        const float* rb = ib + (size_t)(tile0 + vr) * WW + vc;
        f32x4 a0 = *(const f32x4*)(rb);
        f32x4 a1 = *(const f32x4*)(rb + HW);
        f32x4 a2 = *(const f32x4*)(rb + 2 * HW);
        f32x4 q;
        q.x = fmaxf(fmaxf(a0.x, a1.x), a2.x);
        q.y = fmaxf(fmaxf(a0.y, a1.y), a2.y);
        q.z = fmaxf(fmaxf(a0.z, a1.z), a2.z);
        q.w = fmaxf(fmaxf(a0.w, a1.w), a2.w);
        *(f32x4*)&ld[vr * WW + vc] = q;
    }
    __syncthreads();

    // ---- compute + store: 8 iterations of (2 rows x 512 cols) ----
    int c  = hc;
    int cl = hcl, cr = hcr;
    int rb2 = t >> 7;                   // 0 or 1 (wave-uniform)
    size_t planep = (size_t)((f * BB + b) * 2) * HW;
    float* outp = out + planep;
    float* outn = outp + HW;

    #pragma unroll
    for (int j = 0; j < 8; ++j) {
        int orow = (j << 1) + rb2;      // 0..15 within tile; output row tile0+orow
        const float* T = &ld[max(orow - 1, 0) * WW];   // row tile0+orow-1
        const float* M = &ld[orow * WW];               // row tile0+orow
        const float* P = &ld[min(orow + 1, TR - 1) * WW]; // row tile0+orow+1
        float vt[6], vm[6], vp[6];
        if (j == 0 && t < 128) {        // orow==0: top halo from registers
            #pragma unroll
            for (int q2 = 0; q2 < 6; ++q2) vt[q2] = hal[q2];
        } else {
            f32x4 q = *(const f32x4*)(T + c);
            vt[0] = T[cl]; vt[1] = q.x; vt[2] = q.y; vt[3] = q.z; vt[4] = q.w; vt[5] = T[cr];
        }
        { f32x4 q = *(const f32x4*)(M + c);
          vm[0] = M[cl]; vm[1] = q.x; vm[2] = q.y; vm[3] = q.z; vm[4] = q.w; vm[5] = M[cr]; }
        if (j == 7 && t >= 128) {       // orow==15: bottom halo from registers
            #pragma unroll
            for (int q2 = 0; q2 < 6; ++q2) vp[q2] = hal[q2];
        } else {
            f32x4 q = *(const f32x4*)(P + c);
            vp[0] = P[cl]; vp[1] = q.x; vp[2] = q.y; vp[3] = q.z; vp[4] = q.w; vp[5] = P[cr];
        }

        float d0, d1, d2, d3;
        switch (f) {   // formulas verified absmax==0.0 in rounds 1-10
            case 0: d0 = vm[0]-vp[2]; d1 = vm[1]-vp[3]; d2 = vm[2]-vp[4]; d3 = vm[3]-vp[5]; break;
            case 1: d0 = vt[2]-vm[0]; d1 = vt[3]-vm[1]; d2 = vt[4]-vm[2]; d3 = vt[5]-vm[3]; break;
            case 2: d0 = vp[1]-vt[2]; d1 = vp[2]-vt[3]; d2 = vp[3]-vt[4]; d3 = vp[4]-vt[5]; break;
            case 3: d0 = vt[0]-vp[1]; d1 = vt[1]-vp[2]; d2 = vt[2]-vp[3]; d3 = vt[3]-vp[4]; break;
            case 4: d0 = vm[2]-vm[1]; d1 = vm[3]-vm[2]; d2 = vm[4]-vm[3]; d3 = vm[5]-vm[4]; break;
            case 5: d0 = vt[1]-vm[1]; d1 = vt[2]-vm[2]; d2 = vt[3]-vm[3]; d3 = vt[4]-vm[4]; break;
            case 6: d0 = vt[2]-vm[1]; d1 = vt[3]-vm[2]; d2 = vt[4]-vm[3]; d3 = vt[5]-vm[4]; break;
            default:d0 = vt[0]-vm[1]; d1 = vt[1]-vm[2]; d2 = vt[2]-vm[3]; d3 = vt[3]-vm[4]; break;
        }
        f32x4 qp, qn;
        qp.x = (fmaxf(d0, 0.f) >= thr) ? 1.f : 0.f;
        qp.y = (fmaxf(d1, 0.f) >= thr) ? 1.f : 0.f;
        qp.z = (fmaxf(d2, 0.f) >= thr) ? 1.f : 0.f;
        qp.w = (fmaxf(d3, 0.f) >= thr) ? 1.f : 0.f;
        qn.x = (fmaxf(-d0, 0.f) >= thr) ? 1.f : 0.f;
        qn.y = (fmaxf(-d1, 0.f) >= thr) ? 1.f : 0.f;
        qn.z = (fmaxf(-d2, 0.f) >= thr) ? 1.f : 0.f;
        qn.w = (fmaxf(-d3, 0.f) >= thr) ? 1.f : 0.f;

        size_t po = (size_t)(tile0 + orow) * WW + c;
        *(f32x4*)(outp + po) = qp;
        *(f32x4*)(outn + po) = qn;
    }
}

extern "C" void kernel_launch(void* const* d_in, const int* in_sizes, int n_in,
                              void* d_out, int out_size, void* d_ws, size_t ws_size,
                              hipStream_t stream) {
    const float* img = (const float*)d_in[0];
    float* out  = (float*)d_out;
    float* pmin = (float*)d_ws;
    float* pmax = (float*)((char*)d_ws + 16384);

    k1_minmax<<<4096, 256, 0, stream>>>(img, pmin, pmax);
    k2_edges<<<8 * BB * TILES, 256, 0, stream>>>(img, pmin, pmax, out);
}

// Round 12
// 65.656 us; speedup vs baseline: 2.6696x; 1.0167x over previous
//
#include <hip/hip_runtime.h>
#include <cstdint>
#include <cstddef>

typedef float f32x4 __attribute__((ext_vector_type(4)));

constexpr int BB = 16, CC = 3, HH = 512, WW = 512;
constexpr int HW = HH * WW;
constexpr float RATIO = 0.12f;
constexpr int TR = 16;               // rows per k2 tile
constexpr int TILES = HH / TR;       // 32 tiles per image

// ws layout: pmin[4096] @0, pmax[4096] @16384.  No imgv: k2 recomputes
// channel-max from img (L3-resident after k1) during LDS staging.
//
// CHAMPION STRUCTURE (round 6, 65.6us).  Refuted levers (do not retry):
// NT stores (r2,r7), global/per-image barriers (r3,r9), TR=8 (r8),
// filter-pair staging (r10), 5 blocks/CU reg-halo (r11).

__global__ __launch_bounds__(256) void k1_minmax(
        const float* __restrict__ img, float* __restrict__ pmin,
        float* __restrict__ pmax) {
    int t    = blockIdx.x * 256 + threadIdx.x;
    int off4 = t << 2;                 // 4 pixels per thread
    int b    = off4 / HW;              // uniform per block (256 blocks/image)
    int off  = off4 - b * HW;
    const float* base = img + (size_t)b * CC * HW + off;
    f32x4 c0 = *(const f32x4*)(base);
    f32x4 c1 = *(const f32x4*)(base + HW);
    f32x4 c2 = *(const f32x4*)(base + 2 * HW);
    f32x4 v;
    v.x = fmaxf(fmaxf(c0.x, c1.x), c2.x);
    v.y = fmaxf(fmaxf(c0.y, c1.y), c2.y);
    v.z = fmaxf(fmaxf(c0.z, c1.z), c2.z);
    v.w = fmaxf(fmaxf(c0.w, c1.w), c2.w);

    float mn = fminf(fminf(v.x, v.y), fminf(v.z, v.w));
    float mx = fmaxf(fmaxf(v.x, v.y), fmaxf(v.z, v.w));
    #pragma unroll
    for (int s = 32; s > 0; s >>= 1) {
        mn = fminf(mn, __shfl_xor(mn, s, 64));
        mx = fmaxf(mx, __shfl_xor(mx, s, 64));
    }
    __shared__ float smn[4], smx[4];
    int wave = threadIdx.x >> 6;
    if ((threadIdx.x & 63) == 0) { smn[wave] = mn; smx[wave] = mx; }
    __syncthreads();
    if (threadIdx.x == 0) {
        pmin[blockIdx.x] = fminf(fminf(smn[0], smn[1]), fminf(smn[2], smn[3]));
        pmax[blockIdx.x] = fmaxf(fmaxf(smx[0], smx[1]), fmaxf(smx[2], smx[3]));
    }
}

// One block = one (filter, image, 16-row tile); writes only its pos/neg plane
// pair (2 contiguous 32KB streams).  The 8 filter variants of one (image,tile)
// group land on the SAME XCD (bid mod 8): first member pulls the img tile from
// the clean L3 copy, the other 7 hit that XCD's L2.  Channel-max recomputed
// during staging.  Plain cached stores (NT measured slower twice).
__global__ __launch_bounds__(256, 4) void k2_edges(
        const float* __restrict__ img, const float* __restrict__ pmin,
        const float* __restrict__ pmax, float* __restrict__ out) {
    int bid = blockIdx.x;
    int x   = bid & 7;                  // XCD slot
    int m   = bid >> 3;
    int f   = m & 7;                    // filter
    int g   = ((m >> 3) << 3) + x;      // group 0..511 = (image,tile)
    int b    = g >> 5;
    int tile = g & 31;
    int t    = threadIdx.x;

    // ---- per-image threshold from k1's 256 partials ----
    __shared__ float sred[8];
    {
        float mlo = pmin[(b << 8) + t];
        float mhi = pmax[(b << 8) + t];
        #pragma unroll
        for (int s = 32; s > 0; s >>= 1) {
            mlo = fminf(mlo, __shfl_xor(mlo, s, 64));
            mhi = fmaxf(mhi, __shfl_xor(mhi, s, 64));
        }
        if ((t & 63) == 0) { sred[t >> 6] = mlo; sred[4 + (t >> 6)] = mhi; }
    }

    // ---- stage 18 channel-max rows (tile + halo, row-clamped) into LDS ----
    __shared__ float ld[(TR + 2) * WW];   // 36864 B
    int tile0 = tile * TR;
    const float* ib = img + (size_t)b * CC * HW;
    #pragma unroll
    for (int s = 0; s < 9; ++s) {
        int v  = t + (s << 8);          // vec4 index 0..2303
        int vr = v >> 7;                // lds row 0..17
        int vc = (v & 127) << 2;        // col 0..508
        int g2 = min(max(tile0 - 1 + vr, 0), HH - 1);
        const float* rb = ib + (size_t)g2 * WW + vc;
        f32x4 a0 = *(const f32x4*)(rb);
        f32x4 a1 = *(const f32x4*)(rb + HW);
        f32x4 a2 = *(const f32x4*)(rb + 2 * HW);
        f32x4 q;
        q.x = fmaxf(fmaxf(a0.x, a1.x), a2.x);
        q.y = fmaxf(fmaxf(a0.y, a1.y), a2.y);
        q.z = fmaxf(fmaxf(a0.z, a1.z), a2.z);
        q.w = fmaxf(fmaxf(a0.w, a1.w), a2.w);
        *(f32x4*)&ld[vr * WW + vc] = q;
    }
    __syncthreads();
    float thr = (fmaxf(fmaxf(sred[4], sred[5]), fmaxf(sred[6], sred[7]))
               - fminf(fminf(sred[0], sred[1]), fminf(sred[2], sred[3]))) * RATIO;

    // ---- compute + store: 8 iterations of (2 rows x 512 cols) ----
    int c  = (t & 127) << 2;
    int cl = max(c - 1, 0), cr = min(c + 4, WW - 1);
    int rb2 = t >> 7;                   // 0 or 1
    size_t planep = (size_t)((f * BB + b) * 2) * HW;
    float* outp = out + planep;
    float* outn = out + planep + HW;

    #pragma unroll
    for (int j = 0; j < 8; ++j) {
        int orow = (j << 1) + rb2;      // 0..15 within tile
        const float* T = &ld[orow * WW];        // global row rr-1 (clamped)
        const float* M = &ld[(orow + 1) * WW];  // global row rr
        const float* P = &ld[(orow + 2) * WW];  // global row rr+1 (clamped)
        float vt[6], vm[6], vp[6];
        { f32x4 q = *(const f32x4*)(T + c);
          vt[0] = T[cl]; vt[1] = q.x; vt[2] = q.y; vt[3] = q.z; vt[4] = q.w; vt[5] = T[cr]; }
        { f32x4 q = *(const f32x4*)(M + c);
          vm[0] = M[cl]; vm[1] = q.x; vm[2] = q.y; vm[3] = q.z; vm[4] = q.w; vm[5] = M[cr]; }
        { f32x4 q = *(const f32x4*)(P + c);
          vp[0] = P[cl]; vp[1] = q.x; vp[2] = q.y; vp[3] = q.z; vp[4] = q.w; vp[5] = P[cr]; }

        float d0, d1, d2, d3;
        switch (f) {   // formulas verified absmax==0.0 in rounds 1-11
            case 0: d0 = vm[0]-vp[2]; d1 = vm[1]-vp[3]; d2 = vm[2]-vp[4]; d3 = vm[3]-vp[5]; break;
            case 1: d0 = vt[2]-vm[0]; d1 = vt[3]-vm[1]; d2 = vt[4]-vm[2]; d3 = vt[5]-vm[3]; break;
            case 2: d0 = vp[1]-vt[2]; d1 = vp[2]-vt[3]; d2 = vp[3]-vt[4]; d3 = vp[4]-vt[5]; break;
            case 3: d0 = vt[0]-vp[1]; d1 = vt[1]-vp[2]; d2 = vt[2]-vp[3]; d3 = vt[3]-vp[4]; break;
            case 4: d0 = vm[2]-vm[1]; d1 = vm[3]-vm[2]; d2 = vm[4]-vm[3]; d3 = vm[5]-vm[4]; break;
            case 5: d0 = vt[1]-vm[1]; d1 = vt[2]-vm[2]; d2 = vt[3]-vm[3]; d3 = vt[4]-vm[4]; break;
            case 6: d0 = vt[2]-vm[1]; d1 = vt[3]-vm[2]; d2 = vt[4]-vm[3]; d3 = vt[5]-vm[4]; break;
            default:d0 = vt[0]-vm[1]; d1 = vt[1]-vm[2]; d2 = vt[2]-vm[3]; d3 = vt[3]-vm[4]; break;
        }
        f32x4 qp, qn;
        qp.x = (fmaxf(d0, 0.f) >= thr) ? 1.f : 0.f;
        qp.y = (fmaxf(d1, 0.f) >= thr) ? 1.f : 0.f;
        qp.z = (fmaxf(d2, 0.f) >= thr) ? 1.f : 0.f;
        qp.w = (fmaxf(d3, 0.f) >= thr) ? 1.f : 0.f;
        qn.x = (fmaxf(-d0, 0.f) >= thr) ? 1.f : 0.f;
        qn.y = (fmaxf(-d1, 0.f) >= thr) ? 1.f : 0.f;
        qn.z = (fmaxf(-d2, 0.f) >= thr) ? 1.f : 0.f;
        qn.w = (fmaxf(-d3, 0.f) >= thr) ? 1.f : 0.f;

        size_t po = (size_t)(tile0 + orow) * WW + c;
        *(f32x4*)(outp + po) = qp;
        *(f32x4*)(outn + po) = qn;
    }
}

extern "C" void kernel_launch(void* const* d_in, const int* in_sizes, int n_in,
                              void* d_out, int out_size, void* d_ws, size_t ws_size,
                              hipStream_t stream) {
    const float* img = (const float*)d_in[0];
    float* out  = (float*)d_out;
    float* pmin = (float*)d_ws;
    float* pmax = (float*)((char*)d_ws + 16384);

    k1_minmax<<<4096, 256, 0, stream>>>(img, pmin, pmax);
    k2_edges<<<8 * BB * TILES, 256, 0, stream>>>(img, pmin, pmax, out);
}